// Round 5
// baseline (515.660 us; speedup 1.0000x reference)
//
#include <hip/hip_runtime.h>
#include <hip/hip_bf16.h>

#define N_NODES 50000
#define N_EDGES 800000
#define IN_DIM 64
#define HID_DIM 128
#define OUT_DIM 64
#define NGRP 8
#define NE8 (NGRP * N_NODES)                  // 400000 group-major degree entries
#define NBLK8 ((NE8 + 255) / 256)             // 1563 scan blocks
#define MAXE 256                              // per-wave compacted edge cap

// ---- device-global scratch (no ws_size dependence) ----
__device__ int g_in_f32;
__device__ int g_is64;
__device__ int g_src[N_EDGES];
__device__ int g_dst[N_EDGES];
__device__ int g_csr[N_EDGES];
__device__ int g_deg8[NE8];                   // [g][v] group-major
__device__ int g_rowptr8[NE8 + 1];
__device__ int g_cursor8[NE8];
__device__ int g_bsum[NBLK8];
__device__ int g_boff[NBLK8];
__device__ float g_dinv[N_NODES];
__device__ __align__(16) float g_W1f[IN_DIM * HID_DIM];
__device__ __align__(16) float g_W2f[HID_DIM * OUT_DIM];
__device__ __align__(16) float g_b1f[HID_DIM];
__device__ __align__(16) float g_b2f[OUT_DIM];
// g_hs1: aggz out blocked [8][N][8] (N*64), later hs2 blocked (N*64)
__device__ __align__(16) float g_hs1[(size_t)N_NODES * HID_DIM];
// g_agg1: zb blocked [8][N][8] (N*64) during aggz, later h (N*128)
__device__ __align__(16) float g_agg1[(size_t)N_NODES * HID_DIM];

__device__ __forceinline__ float loadx(const void* p, int i, int f32) {
    if (f32) return ((const float*)p)[i];
    unsigned int u = ((unsigned int)((const unsigned short*)p)[i]) << 16;
    return __uint_as_float(u);
}

// ---- dtype / index-width detection (data-driven, deterministic) ----
__global__ void detect_kernel(const unsigned short* __restrict__ zw,
                              const unsigned int* __restrict__ ew, int E) {
    __shared__ int s_f32, s_nz;
    if (threadIdx.x == 0) { s_f32 = 0; s_nz = 0; }
    __syncthreads();
    int hit = 0;
    for (int k = 0; k < 64; k++) {
        int i = 2 * ((threadIdx.x * 64 + k) * 97);
        if (((zw[i] >> 7) & 0xFF) == 0xFF) hit = 1;
    }
    if (hit) atomicOr(&s_f32, 1);
    int nz = 0;
    int step = E / 4096;
    for (int k = 0; k < 4; k++) {
        int idx = 1 + 2 * ((threadIdx.x * 4 + k) * step);
        if (ew[idx] != 0) nz = 1;
    }
    if (nz) atomicOr(&s_nz, 1);
    __syncthreads();
    if (threadIdx.x == 0) { g_in_f32 = s_f32; g_is64 = (s_nz == 0) ? 1 : 0; }
}

// ---- zero deg8 + convert weights/biases to f32 scratch (after detect) ----
__global__ void prep_kernel(const void* __restrict__ W1, const void* __restrict__ b1,
                            const void* __restrict__ W2, const void* __restrict__ b2) {
    int i = blockIdx.x * blockDim.x + threadIdx.x;
    if (i < NE8) g_deg8[i] = 0;
    int f32 = g_in_f32;
    if (i < IN_DIM * HID_DIM) g_W1f[i] = loadx(W1, i, f32);
    if (i < HID_DIM * OUT_DIM) g_W2f[i] = loadx(W2, i, f32);
    if (i < HID_DIM) g_b1f[i] = loadx(b1, i, f32);
    if (i < OUT_DIM) g_b2f[i] = loadx(b2, i, f32);
}

// ---- normalize edge_index to int32 + fused per-group degree count ----
__global__ void convert_kernel(const void* __restrict__ ei, int N, int E) {
    int e = blockIdx.x * blockDim.x + threadIdx.x;
    if (e < E) {
        int s, d;
        if (g_is64) {
            const long long* p = (const long long*)ei;
            s = (int)p[e];
            d = (int)p[E + e];
        } else {
            const int* p = (const int*)ei;
            s = p[e];
            d = p[E + e];
        }
        g_src[e] = s;
        g_dst[e] = d;
        int g = blockIdx.x & (NGRP - 1);
        atomicAdd(&g_deg8[g * N + d], 1);
    }
}

// ---- dinv from summed per-group degrees ----
__global__ void dinv_kernel(int N) {
    int v = blockIdx.x * blockDim.x + threadIdx.x;
    if (v < N) {
        int s = 0;
#pragma unroll
        for (int g = 0; g < NGRP; g++) s += g_deg8[g * N + v];
        g_dinv[v] = rsqrtf((float)s + 1.0f);  // +1 = self loop
    }
}

// ---- phase A: per-block exclusive scan of deg8 ----
__global__ __launch_bounds__(256) void localscan_kernel(int NE) {
    __shared__ int sc[256];
    int t = threadIdx.x;
    int idx = blockIdx.x * 256 + t;
    int d = (idx < NE) ? g_deg8[idx] : 0;
    sc[t] = d;
    __syncthreads();
    for (int off = 1; off < 256; off <<= 1) {
        int v = (t >= off) ? sc[t - off] : 0;
        __syncthreads();
        sc[t] += v;
        __syncthreads();
    }
    if (idx < NE) g_rowptr8[idx] = sc[t] - d;  // local exclusive prefix
    if (t == 255) g_bsum[blockIdx.x] = sc[255];
}

// ---- phase B: scan block sums, 8 values/thread serial + one 256-scan ----
__global__ __launch_bounds__(256) void bscan_kernel(int NB, int NE, int E) {
    __shared__ int sc[256];
    int t = threadIdx.x;
    int loc[8];
    int s = 0;
#pragma unroll
    for (int j = 0; j < 8; j++) {
        int i = t * 8 + j;
        int v = (i < NB) ? g_bsum[i] : 0;
        loc[j] = s;  // exclusive within chunk
        s += v;
    }
    sc[t] = s;
    __syncthreads();
    for (int off = 1; off < 256; off <<= 1) {
        int v = (t >= off) ? sc[t - off] : 0;
        __syncthreads();
        sc[t] += v;
        __syncthreads();
    }
    int excl = sc[t] - s;
#pragma unroll
    for (int j = 0; j < 8; j++) {
        int i = t * 8 + j;
        if (i < NB) g_boff[i] = excl + loc[j];
    }
    if (t == 0) g_rowptr8[NE] = E;
}

// ---- phase C: add block offsets; finalize rowptr8 + cursor8 ----
__global__ __launch_bounds__(256) void addoff_kernel(int NE) {
    int idx = blockIdx.x * 256 + threadIdx.x;
    if (idx < NE) {
        int base = g_rowptr8[idx] + g_boff[blockIdx.x];
        g_rowptr8[idx] = base;
        g_cursor8[idx] = base;
    }
}

// ---- scatter edges into group-partitioned CSR buckets (XCD write locality) ----
__global__ void scatter_kernel(int N, int E) {
    int e = blockIdx.x * blockDim.x + threadIdx.x;
    if (e < E) {
        int g = blockIdx.x & (NGRP - 1);
        int pos = atomicAdd(&g_cursor8[g * N + g_dst[e]], 1);
        g_csr[pos] = g_src[e];
    }
}

// ---- zb[g][node][8] = z[node][g*8+off] * dinv[node]  (blocked, f32) -> g_agg1 ----
__global__ void zprep_kernel(const void* __restrict__ z, int N) {
    int i = blockIdx.x * blockDim.x + threadIdx.x;
    if (i < N * IN_DIM) {
        int node = i >> 6, c = i & 63;
        int g = c >> 3, off = c & 7;
        g_agg1[(size_t)g * (N * 8) + node * 8 + off] = loadx(z, i, g_in_f32) * g_dinv[node];
    }
}

// ---- sliced aggregation core: wave = (node, colgroup); lane = (eslot 0..7, col 0..7)
// colgroup pinned to XCD via blockIdx&7 -> per-XCD 1.6MB slice stays L2-resident
template <int SELF_SCALED>
__device__ __forceinline__ void agg_slice(const float* __restrict__ slice, float* __restrict__ dst,
                                          int wid, int g, int lane, int* buf, int N) {
    int mybeg = 0, mycnt = 0;
    if (lane < NGRP) {
        mybeg = g_rowptr8[lane * N + wid];
        mycnt = g_rowptr8[lane * N + wid + 1] - mybeg;
    }
    int incl = mycnt;
#pragma unroll
    for (int off = 1; off < NGRP; off <<= 1) {
        int v = __shfl_up(incl, off, 64);
        if (lane >= off) incl += v;
    }
    int total = __shfl(incl, NGRP - 1, 64);
    int myoff = incl - mycnt;
    int col = lane & 7;
    int eslot = lane >> 3;
    float acc = 0.f, acc2 = 0.f;
    if (total <= MAXE) {
        if (lane < NGRP) {
            for (int i = 0; i < mycnt; i++) buf[myoff + i] = g_csr[mybeg + i];
        }
        int j = eslot;
        for (; j + 8 < total; j += 16) {
            int s0 = buf[j], s1 = buf[j + 8];
            acc += slice[s0 * 8 + col];
            acc2 += slice[s1 * 8 + col];
        }
        if (j < total) acc += slice[buf[j] * 8 + col];
    } else {  // essentially-never fallback: broadcast walk, lanes<8 accumulate
        for (int gg = 0; gg < NGRP; gg++) {
            int beg = g_rowptr8[gg * N + wid], end = g_rowptr8[gg * N + wid + 1];
            for (int e = beg; e < end; e++) {
                int s = g_csr[e];
                if (lane < 8) acc += slice[s * 8 + col];
            }
        }
    }
    acc += acc2;
    acc += __shfl_xor(acc, 8, 64);
    acc += __shfl_xor(acc, 16, 64);
    acc += __shfl_xor(acc, 32, 64);
    if (lane < 8) {
        float v = (acc + slice[wid * 8 + col]) * g_dinv[wid];
        dst[wid * 8 + col] = v;
    }
}

// ---- layer-1 sliced aggregation: reads zb (g_agg1), writes hs1 blocked (g_hs1) ----
__global__ __launch_bounds__(256) void aggz_kernel(int N) {
    __shared__ int idxbuf[4][MAXE];
    int g = blockIdx.x & (NGRP - 1);
    int w = threadIdx.x >> 6;
    int wid = (blockIdx.x >> 3) * 4 + w;
    if (wid >= N) return;
    int lane = threadIdx.x & 63;
    const float* slice = g_agg1 + (size_t)g * (N * 8);
    float* dst = g_hs1 + (size_t)g * (N * 8);
    agg_slice<1>(slice, dst, wid, g, lane, idxbuf[w], N);
}

// ---- h = relu(aggz @ W1 + b1): 32 rows/block, 4x4 micro-tile, W from L1/L2 ----
__global__ __launch_bounds__(256) void gemm1_kernel(int N) {
    __shared__ float Zs[IN_DIM * 33];  // transposed 64k x 32r, pad 33 -> 8448 B
    int t = threadIdx.x;
    int row0 = blockIdx.x * 32;
#pragma unroll
    for (int s = 0; s < 2; s++) {
        int i = t + s * 256;          // 512 float4s = 32 rows x 16
        int r = i >> 4, k4 = i & 15;
        int row = row0 + r;
        int g = k4 >> 1, off = (k4 & 1) * 4;  // blocked layout [8][N][8]
        float4 v = make_float4(0.f, 0.f, 0.f, 0.f);
        if (row < N) v = *(const float4*)&g_hs1[(size_t)g * (N * 8) + row * 8 + off];
        Zs[(g * 8 + off + 0) * 33 + r] = v.x;
        Zs[(g * 8 + off + 1) * 33 + r] = v.y;
        Zs[(g * 8 + off + 2) * 33 + r] = v.z;
        Zs[(g * 8 + off + 3) * 33 + r] = v.w;
    }
    __syncthreads();
    int cg = t & 31, rg = t >> 5;  // 32 colgroups x 8 rowgroups
    int c0 = cg * 4, r0 = rg * 4;
    float acc[4][4] = {};
#pragma unroll 8
    for (int k = 0; k < IN_DIM; k++) {
        float b[4];
        *(float4*)b = *(const float4*)&g_W1f[k * HID_DIM + c0];
        float a[4];
        a[0] = Zs[k * 33 + r0];
        a[1] = Zs[k * 33 + r0 + 1];
        a[2] = Zs[k * 33 + r0 + 2];
        a[3] = Zs[k * 33 + r0 + 3];
#pragma unroll
        for (int i = 0; i < 4; i++)
#pragma unroll
            for (int j = 0; j < 4; j++) acc[i][j] = fmaf(a[i], b[j], acc[i][j]);
    }
    float4 bias = *(const float4*)&g_b1f[c0];
#pragma unroll
    for (int i = 0; i < 4; i++) {
        int row = row0 + r0 + i;
        if (row < N) {
            float4 v;
            v.x = fmaxf(acc[i][0] + bias.x, 0.f);
            v.y = fmaxf(acc[i][1] + bias.y, 0.f);
            v.z = fmaxf(acc[i][2] + bias.z, 0.f);
            v.w = fmaxf(acc[i][3] + bias.w, 0.f);
            *(float4*)&g_agg1[(size_t)row * HID_DIM + c0] = v;
        }
    }
}

// ---- hs2 = (h @ W2) * dinv: 32 rows/block, 2x4 micro-tile, blocked output ----
__global__ __launch_bounds__(256) void gemm2_kernel(int N) {
    __shared__ float Zs[64 * 33];  // transposed 64k x 32r, pad 33 -> 8448 B
    int t = threadIdx.x;
    int row0 = blockIdx.x * 32;
    int cg = t & 15, rg = t >> 4;  // 16 colgroups x 16 rowgroups
    int c0 = cg * 4, r0 = rg * 2;
    float acc[2][4] = {};
    for (int kh = 0; kh < 2; kh++) {
        __syncthreads();
#pragma unroll
        for (int s = 0; s < 2; s++) {
            int i = t + s * 256;      // 512 float4s = 32 rows x 16
            int r = i >> 4, k4 = i & 15;
            int row = row0 + r;
            float4 v = make_float4(0.f, 0.f, 0.f, 0.f);
            if (row < N) v = *(const float4*)&g_agg1[(size_t)row * HID_DIM + kh * 64 + k4 * 4];
            Zs[(k4 * 4 + 0) * 33 + r] = v.x;
            Zs[(k4 * 4 + 1) * 33 + r] = v.y;
            Zs[(k4 * 4 + 2) * 33 + r] = v.z;
            Zs[(k4 * 4 + 3) * 33 + r] = v.w;
        }
        __syncthreads();
#pragma unroll 8
        for (int k2 = 0; k2 < 64; k2++) {
            float b[4];
            *(float4*)b = *(const float4*)&g_W2f[(kh * 64 + k2) * OUT_DIM + c0];
            float a[2];
            a[0] = Zs[k2 * 33 + r0];
            a[1] = Zs[k2 * 33 + r0 + 1];
#pragma unroll
            for (int i = 0; i < 2; i++)
#pragma unroll
                for (int j = 0; j < 4; j++) acc[i][j] = fmaf(a[i], b[j], acc[i][j]);
        }
    }
    int gg = cg >> 1, off = (cg & 1) * 4;  // blocked output [8][N][8]
#pragma unroll
    for (int i = 0; i < 2; i++) {
        int row = row0 + r0 + i;
        if (row < N) {
            float dn = g_dinv[row];
            float4 v;
            v.x = acc[i][0] * dn;
            v.y = acc[i][1] * dn;
            v.z = acc[i][2] * dn;
            v.w = acc[i][3] * dn;
            *(float4*)&g_hs1[(size_t)gg * (N * 8) + row * 8 + off] = v;
        }
    }
}

// ---- layer-2 sliced aggregation: reads hs2 blocked (g_hs1), writes out + bias ----
__global__ __launch_bounds__(256) void agg2_kernel(void* __restrict__ out, int N) {
    __shared__ int idxbuf[4][MAXE];
    int g = blockIdx.x & (NGRP - 1);
    int w = threadIdx.x >> 6;
    int wid = (blockIdx.x >> 3) * 4 + w;
    if (wid >= N) return;
    int lane = threadIdx.x & 63;
    const float* slice = g_hs1 + (size_t)g * (N * 8);
    int* buf = idxbuf[w];
    int mybeg = 0, mycnt = 0;
    if (lane < NGRP) {
        mybeg = g_rowptr8[lane * N + wid];
        mycnt = g_rowptr8[lane * N + wid + 1] - mybeg;
    }
    int incl = mycnt;
#pragma unroll
    for (int off = 1; off < NGRP; off <<= 1) {
        int v = __shfl_up(incl, off, 64);
        if (lane >= off) incl += v;
    }
    int total = __shfl(incl, NGRP - 1, 64);
    int myoff = incl - mycnt;
    int col = lane & 7;
    int eslot = lane >> 3;
    float acc = 0.f, acc2 = 0.f;
    if (total <= MAXE) {
        if (lane < NGRP) {
            for (int i = 0; i < mycnt; i++) buf[myoff + i] = g_csr[mybeg + i];
        }
        int j = eslot;
        for (; j + 8 < total; j += 16) {
            int s0 = buf[j], s1 = buf[j + 8];
            acc += slice[s0 * 8 + col];
            acc2 += slice[s1 * 8 + col];
        }
        if (j < total) acc += slice[buf[j] * 8 + col];
    } else {
        for (int gg2 = 0; gg2 < NGRP; gg2++) {
            int beg = g_rowptr8[gg2 * N + wid], end = g_rowptr8[gg2 * N + wid + 1];
            for (int e = beg; e < end; e++) {
                int s = g_csr[e];
                if (lane < 8) acc += slice[s * 8 + col];
            }
        }
    }
    acc += acc2;
    acc += __shfl_xor(acc, 8, 64);
    acc += __shfl_xor(acc, 16, 64);
    acc += __shfl_xor(acc, 32, 64);
    if (lane < 8) {
        float v = (acc + slice[wid * 8 + col]) * g_dinv[wid] + g_b2f[g * 8 + col];
        int oc = wid * 64 + g * 8 + col;
        if (g_in_f32) ((float*)out)[oc] = v;
        else ((__hip_bfloat16*)out)[oc] = __float2bfloat16(v);
    }
}

extern "C" void kernel_launch(void* const* d_in, const int* in_sizes, int n_in,
                              void* d_out, int out_size, void* d_ws, size_t ws_size,
                              hipStream_t stream) {
    const void* z  = d_in[0];
    const void* ei = d_in[1];
    const void* W1 = d_in[2];
    const void* b1 = d_in[3];
    const void* W2 = d_in[4];
    const void* b2 = d_in[5];

    const int N = in_sizes[0] / IN_DIM;  // 50000
    const int E = in_sizes[1] / 2;       // 800000
    const int NE = NGRP * N;             // 400000
    const int aggblocks = NGRP * ((N + 3) / 4);  // 100000

    detect_kernel<<<1, 256, 0, stream>>>((const unsigned short*)z, (const unsigned int*)ei, E);
    prep_kernel<<<NBLK8, 256, 0, stream>>>(W1, b1, W2, b2);
    convert_kernel<<<(E + 255) / 256, 256, 0, stream>>>(ei, N, E);
    dinv_kernel<<<(N + 255) / 256, 256, 0, stream>>>(N);
    localscan_kernel<<<(NE + 255) / 256, 256, 0, stream>>>(NE);
    bscan_kernel<<<1, 256, 0, stream>>>((NE + 255) / 256, NE, E);
    addoff_kernel<<<(NE + 255) / 256, 256, 0, stream>>>(NE);
    scatter_kernel<<<(E + 255) / 256, 256, 0, stream>>>(N, E);

    zprep_kernel<<<(N * IN_DIM + 255) / 256, 256, 0, stream>>>(z, N);
    aggz_kernel<<<aggblocks, 256, 0, stream>>>(N);
    gemm1_kernel<<<(N + 31) / 32, 256, 0, stream>>>(N);
    gemm2_kernel<<<(N + 31) / 32, 256, 0, stream>>>(N);
    agg2_kernel<<<aggblocks, 256, 0, stream>>>(d_out, N);
}

// Round 6
// 316.909 us; speedup vs baseline: 1.6272x; 1.6272x over previous
//
#include <hip/hip_runtime.h>
#include <hip/hip_bf16.h>

#define N_NODES 50000
#define N_EDGES 800000
#define IN_DIM 64
#define HID_DIM 128
#define OUT_DIM 64
#define NGRP 8
#define NE8 (NGRP * N_NODES)                  // 400000 group-major degree entries
#define NBLK8 ((NE8 + 255) / 256)             // 1563 scan blocks
#define MAXE 128                              // per-wave compacted edge cap

// ---- device-global scratch (no ws_size dependence) ----
__device__ int g_in_f32;
__device__ int g_is64;
__device__ int g_src[N_EDGES];
__device__ int g_dst[N_EDGES];
__device__ int g_csr[N_EDGES];
__device__ int g_deg8[NE8];                   // [g][v] group-major
__device__ int g_rowptr8[NE8 + 1];
__device__ int g_cursor8[NE8];
__device__ int g_bsum[NBLK8];
__device__ int g_boff[NBLK8];
__device__ float g_dinv[N_NODES];
__device__ __align__(16) float g_W1f[IN_DIM * HID_DIM];
__device__ __align__(16) float g_W2f[HID_DIM * OUT_DIM];
__device__ __align__(16) float g_b1f[HID_DIM];
__device__ __align__(16) float g_b2f[OUT_DIM];
__device__ __align__(16) float g_hs1[(size_t)N_NODES * HID_DIM];   // aggz out (N*64), later hs2 (N*64)
__device__ __align__(16) float g_agg1[(size_t)N_NODES * HID_DIM];  // h (N*128)

__device__ __forceinline__ float loadx(const void* p, int i, int f32) {
    if (f32) return ((const float*)p)[i];
    unsigned int u = ((unsigned int)((const unsigned short*)p)[i]) << 16;
    return __uint_as_float(u);
}

// ---- dtype / index-width detection (data-driven, deterministic) ----
__global__ void detect_kernel(const unsigned short* __restrict__ zw,
                              const unsigned int* __restrict__ ew, int E) {
    __shared__ int s_f32, s_nz;
    if (threadIdx.x == 0) { s_f32 = 0; s_nz = 0; }
    __syncthreads();
    int hit = 0;
    for (int k = 0; k < 64; k++) {
        int i = 2 * ((threadIdx.x * 64 + k) * 97);
        if (((zw[i] >> 7) & 0xFF) == 0xFF) hit = 1;
    }
    if (hit) atomicOr(&s_f32, 1);
    int nz = 0;
    int step = E / 4096;
    for (int k = 0; k < 4; k++) {
        int idx = 1 + 2 * ((threadIdx.x * 4 + k) * step);
        if (ew[idx] != 0) nz = 1;
    }
    if (nz) atomicOr(&s_nz, 1);
    __syncthreads();
    if (threadIdx.x == 0) { g_in_f32 = s_f32; g_is64 = (s_nz == 0) ? 1 : 0; }
}

// ---- zero deg8 + convert weights/biases to f32 scratch (after detect) ----
__global__ void prep_kernel(const void* __restrict__ W1, const void* __restrict__ b1,
                            const void* __restrict__ W2, const void* __restrict__ b2) {
    int i = blockIdx.x * blockDim.x + threadIdx.x;
    if (i < NE8) g_deg8[i] = 0;
    int f32 = g_in_f32;
    if (i < IN_DIM * HID_DIM) g_W1f[i] = loadx(W1, i, f32);
    if (i < HID_DIM * OUT_DIM) g_W2f[i] = loadx(W2, i, f32);
    if (i < HID_DIM) g_b1f[i] = loadx(b1, i, f32);
    if (i < OUT_DIM) g_b2f[i] = loadx(b2, i, f32);
}

// ---- normalize edge_index to int32 + fused per-group degree count ----
__global__ void convert_kernel(const void* __restrict__ ei, int N, int E) {
    int e = blockIdx.x * blockDim.x + threadIdx.x;
    if (e < E) {
        int s, d;
        if (g_is64) {
            const long long* p = (const long long*)ei;
            s = (int)p[e];
            d = (int)p[E + e];
        } else {
            const int* p = (const int*)ei;
            s = p[e];
            d = p[E + e];
        }
        g_src[e] = s;
        g_dst[e] = d;
        int g = blockIdx.x & (NGRP - 1);
        atomicAdd(&g_deg8[g * N + d], 1);
    }
}

// ---- dinv from summed per-group degrees ----
__global__ void dinv_kernel(int N) {
    int v = blockIdx.x * blockDim.x + threadIdx.x;
    if (v < N) {
        int s = 0;
#pragma unroll
        for (int g = 0; g < NGRP; g++) s += g_deg8[g * N + v];
        g_dinv[v] = rsqrtf((float)s + 1.0f);  // +1 = self loop
    }
}

// ---- phase A: per-block exclusive scan of deg8 ----
__global__ __launch_bounds__(256) void localscan_kernel(int NE) {
    __shared__ int sc[256];
    int t = threadIdx.x;
    int idx = blockIdx.x * 256 + t;
    int d = (idx < NE) ? g_deg8[idx] : 0;
    sc[t] = d;
    __syncthreads();
    for (int off = 1; off < 256; off <<= 1) {
        int v = (t >= off) ? sc[t - off] : 0;
        __syncthreads();
        sc[t] += v;
        __syncthreads();
    }
    if (idx < NE) g_rowptr8[idx] = sc[t] - d;  // local exclusive prefix
    if (t == 255) g_bsum[blockIdx.x] = sc[255];
}

// ---- phase B: scan block sums, 8 values/thread serial + one 256-scan ----
__global__ __launch_bounds__(256) void bscan_kernel(int NB, int NE, int E) {
    __shared__ int sc[256];
    int t = threadIdx.x;
    int loc[8];
    int s = 0;
#pragma unroll
    for (int j = 0; j < 8; j++) {
        int i = t * 8 + j;
        int v = (i < NB) ? g_bsum[i] : 0;
        loc[j] = s;  // exclusive within chunk
        s += v;
    }
    sc[t] = s;
    __syncthreads();
    for (int off = 1; off < 256; off <<= 1) {
        int v = (t >= off) ? sc[t - off] : 0;
        __syncthreads();
        sc[t] += v;
        __syncthreads();
    }
    int excl = sc[t] - s;
#pragma unroll
    for (int j = 0; j < 8; j++) {
        int i = t * 8 + j;
        if (i < NB) g_boff[i] = excl + loc[j];
    }
    if (t == 0) g_rowptr8[NE] = E;
}

// ---- phase C: add block offsets; finalize rowptr8 + cursor8 ----
__global__ __launch_bounds__(256) void addoff_kernel(int NE) {
    int idx = blockIdx.x * 256 + threadIdx.x;
    if (idx < NE) {
        int base = g_rowptr8[idx] + g_boff[blockIdx.x];
        g_rowptr8[idx] = base;
        g_cursor8[idx] = base;
    }
}

// ---- scatter edges into group-partitioned CSR buckets (XCD write locality) ----
__global__ void scatter_kernel(int N, int E) {
    int e = blockIdx.x * blockDim.x + threadIdx.x;
    if (e < E) {
        int g = blockIdx.x & (NGRP - 1);
        int pos = atomicAdd(&g_cursor8[g * N + g_dst[e]], 1);
        g_csr[pos] = g_src[e];
    }
}

// ---- layer-1 agg fused with zscale: gather raw z, scale by dinv[src] (LDS-cached) ----
// wave per node; parallel compaction of 8 group ranges; 16-deep gather pipeline
__global__ __launch_bounds__(256) void aggz_kernel(const void* __restrict__ z, int N) {
    __shared__ int idxbuf[4][MAXE];
    __shared__ float dwbuf[4][MAXE];
    __shared__ int goffs[4][NGRP];
    __shared__ int gbegs[4][NGRP];
    int wid = (blockIdx.x * blockDim.x + threadIdx.x) >> 6;
    if (wid >= N) return;
    int lane = threadIdx.x & 63;
    int w = threadIdx.x >> 6;
    int f32 = g_in_f32;
    int mybeg = 0, mycnt = 0;
    if (lane < NGRP) {
        mybeg = g_rowptr8[lane * N + wid];
        mycnt = g_rowptr8[lane * N + wid + 1] - mybeg;
    }
    int incl = mycnt;
#pragma unroll
    for (int off = 1; off < NGRP; off <<= 1) {
        int v = __shfl_up(incl, off, 64);
        if (lane >= off) incl += v;
    }
    int total = __shfl(incl, NGRP - 1, 64);
    if (lane < NGRP) { goffs[w][lane] = incl - mycnt; gbegs[w][lane] = mybeg; }
    int* buf = idxbuf[w];
    float* dbuf = dwbuf[w];
    float self = loadx(z, wid * IN_DIM + lane, f32) * g_dinv[wid];
    float av[8] = {};
    if (total <= MAXE) {
        const int* go = goffs[w];
        const int* gb = gbegs[w];
        for (int i = lane; i < total; i += 64) {
            int g = 0;
#pragma unroll
            for (int k = 1; k < NGRP; k++) g += (i >= go[k]);
            int s = g_csr[gb[g] + i - go[g]];
            buf[i] = s;
            dbuf[i] = g_dinv[s];
        }
        int j = 0;
        for (; j + 16 <= total; j += 16) {
            float vv[16];
#pragma unroll
            for (int u = 0; u < 16; u++) vv[u] = loadx(z, buf[j + u] * IN_DIM + lane, f32);
#pragma unroll
            for (int u = 0; u < 16; u++) av[u & 7] = fmaf(vv[u], dbuf[j + u], av[u & 7]);
        }
        if (j + 8 <= total) {
            float vv[8];
#pragma unroll
            for (int u = 0; u < 8; u++) vv[u] = loadx(z, buf[j + u] * IN_DIM + lane, f32);
#pragma unroll
            for (int u = 0; u < 8; u++) av[u] = fmaf(vv[u], dbuf[j + u], av[u]);
            j += 8;
        }
        if (j + 4 <= total) {
            float vv[4];
#pragma unroll
            for (int u = 0; u < 4; u++) vv[u] = loadx(z, buf[j + u] * IN_DIM + lane, f32);
#pragma unroll
            for (int u = 0; u < 4; u++) av[u] = fmaf(vv[u], dbuf[j + u], av[u]);
            j += 4;
        }
        for (; j < total; j++) av[0] = fmaf(loadx(z, buf[j] * IN_DIM + lane, f32), dbuf[j], av[0]);
    } else {  // essentially-never fallback: serial 8-range walk
        for (int g = 0; g < NGRP; g++) {
            int beg = g_rowptr8[g * N + wid], end = g_rowptr8[g * N + wid + 1];
            for (int e = beg; e < end; e++) {
                int s = g_csr[e];
                av[0] = fmaf(loadx(z, s * IN_DIM + lane, f32), g_dinv[s], av[0]);
            }
        }
    }
    float acc = ((av[0] + av[1]) + (av[2] + av[3])) + ((av[4] + av[5]) + (av[6] + av[7])) + self;
    g_hs1[(size_t)wid * 64 + lane] = acc * g_dinv[wid];
}

// ---- h = relu(aggz @ W1 + b1): 32 rows/block, 4x4 micro-tile, W from L1/L2 ----
__global__ __launch_bounds__(256) void gemm1_kernel(int N) {
    __shared__ float Zs[IN_DIM * 33];  // transposed 64k x 32r, pad 33 -> 8448 B
    int t = threadIdx.x;
    int row0 = blockIdx.x * 32;
    const float* aggz = g_hs1;
#pragma unroll
    for (int s = 0; s < 2; s++) {
        int i = t + s * 256;          // 512 float4s = 32 rows x 16
        int r = i >> 4, k4 = i & 15;
        int row = row0 + r;
        float4 v = make_float4(0.f, 0.f, 0.f, 0.f);
        if (row < N) v = *(const float4*)&aggz[(size_t)row * IN_DIM + k4 * 4];
        Zs[(k4 * 4 + 0) * 33 + r] = v.x;
        Zs[(k4 * 4 + 1) * 33 + r] = v.y;
        Zs[(k4 * 4 + 2) * 33 + r] = v.z;
        Zs[(k4 * 4 + 3) * 33 + r] = v.w;
    }
    __syncthreads();
    int cg = t & 31, rg = t >> 5;  // 32 colgroups x 8 rowgroups
    int c0 = cg * 4, r0 = rg * 4;
    float acc[4][4] = {};
#pragma unroll 8
    for (int k = 0; k < IN_DIM; k++) {
        float b[4];
        *(float4*)b = *(const float4*)&g_W1f[k * HID_DIM + c0];
        float a[4];
        a[0] = Zs[k * 33 + r0];
        a[1] = Zs[k * 33 + r0 + 1];
        a[2] = Zs[k * 33 + r0 + 2];
        a[3] = Zs[k * 33 + r0 + 3];
#pragma unroll
        for (int i = 0; i < 4; i++)
#pragma unroll
            for (int j = 0; j < 4; j++) acc[i][j] = fmaf(a[i], b[j], acc[i][j]);
    }
    float4 bias = *(const float4*)&g_b1f[c0];
#pragma unroll
    for (int i = 0; i < 4; i++) {
        int row = row0 + r0 + i;
        if (row < N) {
            float4 v;
            v.x = fmaxf(acc[i][0] + bias.x, 0.f);
            v.y = fmaxf(acc[i][1] + bias.y, 0.f);
            v.z = fmaxf(acc[i][2] + bias.z, 0.f);
            v.w = fmaxf(acc[i][3] + bias.w, 0.f);
            *(float4*)&g_agg1[(size_t)row * HID_DIM + c0] = v;
        }
    }
}

// ---- hs2 = (h @ W2) * dinv: 32 rows/block, 2x4 micro-tile, K split 2x64 ----
__global__ __launch_bounds__(256) void gemm2_kernel(int N) {
    __shared__ float Zs[64 * 33];  // transposed 64k x 32r, pad 33 -> 8448 B
    int t = threadIdx.x;
    int row0 = blockIdx.x * 32;
    int cg = t & 15, rg = t >> 4;  // 16 colgroups x 16 rowgroups
    int c0 = cg * 4, r0 = rg * 2;
    float acc[2][4] = {};
    for (int kh = 0; kh < 2; kh++) {
        __syncthreads();
#pragma unroll
        for (int s = 0; s < 2; s++) {
            int i = t + s * 256;      // 512 float4s = 32 rows x 16
            int r = i >> 4, k4 = i & 15;
            int row = row0 + r;
            float4 v = make_float4(0.f, 0.f, 0.f, 0.f);
            if (row < N) v = *(const float4*)&g_agg1[(size_t)row * HID_DIM + kh * 64 + k4 * 4];
            Zs[(k4 * 4 + 0) * 33 + r] = v.x;
            Zs[(k4 * 4 + 1) * 33 + r] = v.y;
            Zs[(k4 * 4 + 2) * 33 + r] = v.z;
            Zs[(k4 * 4 + 3) * 33 + r] = v.w;
        }
        __syncthreads();
#pragma unroll 8
        for (int k2 = 0; k2 < 64; k2++) {
            float b[4];
            *(float4*)b = *(const float4*)&g_W2f[(kh * 64 + k2) * OUT_DIM + c0];
            float a[2];
            a[0] = Zs[k2 * 33 + r0];
            a[1] = Zs[k2 * 33 + r0 + 1];
#pragma unroll
            for (int i = 0; i < 2; i++)
#pragma unroll
                for (int j = 0; j < 4; j++) acc[i][j] = fmaf(a[i], b[j], acc[i][j]);
        }
    }
#pragma unroll
    for (int i = 0; i < 2; i++) {
        int row = row0 + r0 + i;
        if (row < N) {
            float dn = g_dinv[row];
            float4 v;
            v.x = acc[i][0] * dn;
            v.y = acc[i][1] * dn;
            v.z = acc[i][2] * dn;
            v.w = acc[i][3] * dn;
            *(float4*)&g_hs1[(size_t)row * OUT_DIM + c0] = v;
        }
    }
}

// ---- layer-2 aggregation: parallel compaction + 16-deep gather; fused bias + store ----
__global__ __launch_bounds__(256) void agg2_kernel(void* __restrict__ out, int N) {
    __shared__ int idxbuf[4][MAXE];
    __shared__ int goffs[4][NGRP];
    __shared__ int gbegs[4][NGRP];
    int wid = (blockIdx.x * blockDim.x + threadIdx.x) >> 6;
    if (wid >= N) return;
    int lane = threadIdx.x & 63;
    int w = threadIdx.x >> 6;
    const float* hs = g_hs1;  // row = 64 floats (already dinv-scaled)
    int mybeg = 0, mycnt = 0;
    if (lane < NGRP) {
        mybeg = g_rowptr8[lane * N + wid];
        mycnt = g_rowptr8[lane * N + wid + 1] - mybeg;
    }
    int incl = mycnt;
#pragma unroll
    for (int off = 1; off < NGRP; off <<= 1) {
        int v = __shfl_up(incl, off, 64);
        if (lane >= off) incl += v;
    }
    int total = __shfl(incl, NGRP - 1, 64);
    if (lane < NGRP) { goffs[w][lane] = incl - mycnt; gbegs[w][lane] = mybeg; }
    int* buf = idxbuf[w];
    float self = hs[(size_t)wid * 64 + lane];
    float av[8] = {};
    if (total <= MAXE) {
        const int* go = goffs[w];
        const int* gb = gbegs[w];
        for (int i = lane; i < total; i += 64) {
            int g = 0;
#pragma unroll
            for (int k = 1; k < NGRP; k++) g += (i >= go[k]);
            buf[i] = g_csr[gb[g] + i - go[g]];
        }
        int j = 0;
        for (; j + 16 <= total; j += 16) {
            float vv[16];
#pragma unroll
            for (int u = 0; u < 16; u++) vv[u] = hs[(size_t)buf[j + u] * 64 + lane];
#pragma unroll
            for (int u = 0; u < 16; u++) av[u & 7] += vv[u];
        }
        if (j + 8 <= total) {
            float vv[8];
#pragma unroll
            for (int u = 0; u < 8; u++) vv[u] = hs[(size_t)buf[j + u] * 64 + lane];
#pragma unroll
            for (int u = 0; u < 8; u++) av[u] += vv[u];
            j += 8;
        }
        if (j + 4 <= total) {
            float vv[4];
#pragma unroll
            for (int u = 0; u < 4; u++) vv[u] = hs[(size_t)buf[j + u] * 64 + lane];
#pragma unroll
            for (int u = 0; u < 4; u++) av[u] += vv[u];
            j += 4;
        }
        for (; j < total; j++) av[0] += hs[(size_t)buf[j] * 64 + lane];
    } else {
        for (int g = 0; g < NGRP; g++) {
            int beg = g_rowptr8[g * N + wid], end = g_rowptr8[g * N + wid + 1];
            for (int e = beg; e < end; e++) av[0] += hs[(size_t)g_csr[e] * 64 + lane];
        }
    }
    float acc = ((av[0] + av[1]) + (av[2] + av[3])) + ((av[4] + av[5]) + (av[6] + av[7])) + self;
    float v = acc * g_dinv[wid] + g_b2f[lane];
    if (g_in_f32) ((float*)out)[(size_t)wid * 64 + lane] = v;
    else ((__hip_bfloat16*)out)[(size_t)wid * 64 + lane] = __float2bfloat16(v);
}

extern "C" void kernel_launch(void* const* d_in, const int* in_sizes, int n_in,
                              void* d_out, int out_size, void* d_ws, size_t ws_size,
                              hipStream_t stream) {
    const void* z  = d_in[0];
    const void* ei = d_in[1];
    const void* W1 = d_in[2];
    const void* b1 = d_in[3];
    const void* W2 = d_in[4];
    const void* b2 = d_in[5];

    const int N = in_sizes[0] / IN_DIM;  // 50000
    const int E = in_sizes[1] / 2;       // 800000
    const int NE = NGRP * N;             // 400000

    detect_kernel<<<1, 256, 0, stream>>>((const unsigned short*)z, (const unsigned int*)ei, E);
    prep_kernel<<<NBLK8, 256, 0, stream>>>(W1, b1, W2, b2);
    convert_kernel<<<(E + 255) / 256, 256, 0, stream>>>(ei, N, E);
    dinv_kernel<<<(N + 255) / 256, 256, 0, stream>>>(N);
    localscan_kernel<<<(NE + 255) / 256, 256, 0, stream>>>(NE);
    bscan_kernel<<<1, 256, 0, stream>>>((NE + 255) / 256, NE, E);
    addoff_kernel<<<(NE + 255) / 256, 256, 0, stream>>>(NE);
    scatter_kernel<<<(E + 255) / 256, 256, 0, stream>>>(N, E);

    aggz_kernel<<<(N * 64 + 255) / 256, 256, 0, stream>>>(z, N);
    gemm1_kernel<<<(N + 31) / 32, 256, 0, stream>>>(N);
    gemm2_kernel<<<(N + 31) / 32, 256, 0, stream>>>(N);
    agg2_kernel<<<(N * 64 + 255) / 256, 256, 0, stream>>>(d_out, N);
}